// Round 14
// baseline (430.011 us; speedup 1.0000x reference)
//
#include <hip/hip_runtime.h>
#include <hip/hip_bf16.h>
#include <math.h>

#define N_NODES 50000
#define DEG 16
#define FIN 256
#define FOUT 128
#define HID 128
#define FG 512            // 4*HID
#define NEDGE (N_NODES*DEG)
#define NCHUNK (N_NODES/16)   // 3125 exactly
#define K5GRID 512            // 2 blocks/CU, independent barrier domains
#define GM 391                // (N_NODES+127)/128
#define G0B (GM*2)            // kgemm0 blocks (bn = 0,1)
#define G1B (GM*4)            // kgemm1 blocks (bn = 0..3)
#define KSB 782               // k_s blocks (64 rows each; 782*64 = 50048 >= N)
#define K34B 196              // k34 blocks ((N+255)/256)

typedef __bf16 bf16x8 __attribute__((ext_vector_type(8)));
typedef float  f32x4  __attribute__((ext_vector_type(4)));

// ---------------- helpers ----------------
static __device__ __forceinline__ float u2f(unsigned int u){ union {unsigned int u; float f;} v; v.u=u; return v.f; }
static __device__ __forceinline__ unsigned int f2u(float f){ union {float f; unsigned int u;} v; v.f=f; return v.u; }
static __device__ __forceinline__ unsigned short f2bfu(float f){  // RNE float->bf16 bits
  unsigned int u = f2u(f);
  unsigned int r = u + 0x7fffu + ((u >> 16) & 1u);
  return (unsigned short)(r >> 16);
}
static __device__ __forceinline__ float bflo(unsigned int u){ return u2f(u << 16); }
static __device__ __forceinline__ float bfhi(unsigned int u){ return u2f(u & 0xffff0000u); }
// fast reciprocal: v_rcp_f32 (<=1 ulp) instead of IEEE div sequence
static __device__ __forceinline__ float rcpf(float x){ return __builtin_amdgcn_rcpf(x); }

// async global->LDS copy, 16B/lane, wave-uniform LDS base + lane*16 dest
static __device__ __forceinline__ void gl_lds16(const void* g, void* l){
  __builtin_amdgcn_global_load_lds(
      (const __attribute__((address_space(1))) unsigned int*)g,
      (__attribute__((address_space(3))) unsigned int*)l, 16, 0, 0);
}

// 8x fp32 -> split-bf16 hi/lo planes
static __device__ __forceinline__ void cvt8(const float4 v0, const float4 v1, uint4* H4, uint4* L4){
  union { unsigned short us[8]; uint4 u4; } H, L;
  H.us[0]=f2bfu(v0.x); L.us[0]=f2bfu(v0.x - u2f((unsigned)H.us[0] << 16));
  H.us[1]=f2bfu(v0.y); L.us[1]=f2bfu(v0.y - u2f((unsigned)H.us[1] << 16));
  H.us[2]=f2bfu(v0.z); L.us[2]=f2bfu(v0.z - u2f((unsigned)H.us[2] << 16));
  H.us[3]=f2bfu(v0.w); L.us[3]=f2bfu(v0.w - u2f((unsigned)H.us[3] << 16));
  H.us[4]=f2bfu(v1.x); L.us[4]=f2bfu(v1.x - u2f((unsigned)H.us[4] << 16));
  H.us[5]=f2bfu(v1.y); L.us[5]=f2bfu(v1.y - u2f((unsigned)H.us[5] << 16));
  H.us[6]=f2bfu(v1.z); L.us[6]=f2bfu(v1.z - u2f((unsigned)H.us[6] << 16));
  H.us[7]=f2bfu(v1.w); L.us[7]=f2bfu(v1.w - u2f((unsigned)H.us[7] << 16));
  *H4 = H.u4; *L4 = L.u4;
}

union FU { bf16x8 bf; unsigned short us[8]; uint4 u4; };

// ---------------- KW: weight converts (ONCE) + v = W^T a (double) ----------------
// Restored from pre-R12: converting W once here removes the per-GEMM-block
// redundant conversion (782x for Wp/Ws, 1564x for wih) that R12 introduced.
__global__ __launch_bounds__(256) void k_w(
    const float* __restrict__ Wp, const float* __restrict__ Ws,
    const float* __restrict__ wih, const float* __restrict__ a_src, const float* __restrict__ a_trg,
    unsigned short* __restrict__ Wch, unsigned short* __restrict__ Wcl,
    unsigned short* __restrict__ wihh, unsigned short* __restrict__ wihl,
    double* __restrict__ vsrc, double* __restrict__ vtrg)
{
  const int b = blockIdx.x, tid = threadIdx.x;
  if (b < 256) {
    const float* src = (b < 128) ? (Wp + b*FIN) : (Ws + (b-128)*FIN);
    const float v = src[tid];
    const unsigned short h = f2bfu(v);
    Wch[b*FIN + tid] = h;
    Wcl[b*FIN + tid] = f2bfu(v - u2f((unsigned)h << 16));
  } else if (b < 512) {
    const int row = (b-256)*2 + (tid >> 7);
    const int k   = tid & 127;
    const float v = wih[row*HID + k];
    const unsigned short h = f2bfu(v);
    wihh[row*HID + k] = h;
    wihl[row*HID + k] = f2bfu(v - u2f((unsigned)h << 16));
  } else {
    const int k = tid;
    double s1 = 0.0, s2 = 0.0;
    for (int i = 0; i < FOUT; ++i) {
      const double w = (double)Wp[i*FIN + k];
      s1 += (double)a_src[i] * w;
      s2 += (double)a_trg[i] * w;
    }
    vsrc[k] = s1; vtrg[k] = s2;
  }
}

// ---------------- GEMM body: split-bf16 MFMA, 128x128 tile, 2 half-passes ----------------
// B from precomputed bf16 planes via gl_lds16 (pre-swizzled global address).
// MODE 0 A: fp32 x reg-staged + converted. MODE 1 A: bf16 planes via gl_lds16.
template<int KD, int MODE>
static __device__ __forceinline__ void gemm_body(
    unsigned short* __restrict__ At0, unsigned short* __restrict__ At1,
    unsigned short* __restrict__ Bt0, unsigned short* __restrict__ Bt1,
    const int bm, const int bn,
    const float* __restrict__ Af32,
    const unsigned short* __restrict__ Ah_g, const unsigned short* __restrict__ Al_g,
    const unsigned short* __restrict__ Bh_g, const unsigned short* __restrict__ Bl_g,
    const float* __restrict__ bias, float* __restrict__ outf,
    unsigned short* __restrict__ o_h, unsigned short* __restrict__ o_l)
{
  const int tid = threadIdx.x;
  const int r0 = bm*128;
  const int wave = tid >> 6, lane = tid & 63, c = lane & 15, q = lane >> 4;
  const int srow = tid >> 3, sg = tid & 7;

  f32x4 acc[2][2][4];   // [half][rt][ct]
  #pragma unroll
  for (int h = 0; h < 2; ++h)
    #pragma unroll
    for (int rt = 0; rt < 2; ++rt)
      #pragma unroll
      for (int ct = 0; ct < 4; ++ct) acc[h][rt][ct] = (f32x4){0.f,0.f,0.f,0.f};

  for (int kt = 0; kt < KD/64; ++kt) {
    const int k0 = kt*64;
    __syncthreads();                       // prev iteration's At/Bt reads done
    if (MODE == 0) {
      #pragma unroll
      for (int rr = 0; rr < 4; ++rr) {
        const int row = rr*32 + srow;
        int grow = r0 + row; if (grow >= N_NODES) grow = N_NODES-1;
        const int ga = grow*KD + k0 + sg*8;
        const int la = row*64 + (((sg ^ (row & 7))) << 3);
        cvt8(*(const float4*)&Af32[ga], *(const float4*)&Af32[ga + 4],
             (uint4*)&At0[la], (uint4*)&At1[la]);
      }
    } else {
      #pragma unroll
      for (int rr = 0; rr < 4; ++rr) {
        const int row = rr*32 + wave*8 + (lane >> 3);
        int grow = r0 + row; if (grow >= N_NODES) grow = N_NODES-1;
        const int sgE = (lane & 7) ^ (row & 7);
        const int ga = grow*KD + k0 + sgE*8;
        const int la = (rr*32 + wave*8)*64;          // wave-uniform
        gl_lds16(&Ah_g[ga], &At0[la]);
        gl_lds16(&Al_g[ga], &At1[la]);
      }
    }

    #pragma unroll
    for (int h = 0; h < 2; ++h) {
      if (h == 1) __syncthreads();         // half-0 Bt reads done before overwrite
      // B half-tile from precomputed planes via gl_lds16
      #pragma unroll
      for (int rr = 0; rr < 2; ++rr) {
        const int row = rr*32 + wave*8 + (lane >> 3);
        const int j = bn*128 + h*64 + row;
        int wr;
        if (MODE == 0) wr = j;                        // Wch = [Wp;Ws], 256 rows
        else wr = (j & 3)*HID + (j >> 2);             // gate-interleaved wih
        const int sgE = (lane & 7) ^ (row & 7);
        const int ga = wr*KD + k0 + sgE*8;
        const int la = (rr*32 + wave*8)*64;           // wave-uniform
        gl_lds16(&Bh_g[ga], &Bt0[la]);
        gl_lds16(&Bl_g[ga], &Bt1[la]);
      }
      __syncthreads();                     // At (h==0) / Bt ready

      #pragma unroll
      for (int s = 0; s < 2; ++s) {
        FU Af[2][2], Bf[4][2];
        #pragma unroll
        for (int rt = 0; rt < 2; ++rt) {
          const int row = wave*32 + rt*16 + c;
          const int ad = row*64 + (((((s<<2)+q) ^ (row & 7))) << 3);
          Af[rt][0].u4 = *(const uint4*)&At0[ad];
          Af[rt][1].u4 = *(const uint4*)&At1[ad];
        }
        #pragma unroll
        for (int ct = 0; ct < 4; ++ct) {
          const int row = ct*16 + c;
          const int ad = row*64 + (((((s<<2)+q) ^ (row & 7))) << 3);
          Bf[ct][0].u4 = *(const uint4*)&Bt0[ad];
          Bf[ct][1].u4 = *(const uint4*)&Bt1[ad];
        }
        #pragma unroll
        for (int rt = 0; rt < 2; ++rt)
          #pragma unroll
          for (int ct = 0; ct < 4; ++ct) {
            acc[h][rt][ct] = __builtin_amdgcn_mfma_f32_16x16x32_bf16(Af[rt][0].bf, Bf[ct][0].bf, acc[h][rt][ct], 0,0,0);
            acc[h][rt][ct] = __builtin_amdgcn_mfma_f32_16x16x32_bf16(Af[rt][1].bf, Bf[ct][0].bf, acc[h][rt][ct], 0,0,0);
            acc[h][rt][ct] = __builtin_amdgcn_mfma_f32_16x16x32_bf16(Af[rt][0].bf, Bf[ct][1].bf, acc[h][rt][ct], 0,0,0);
          }
      }
    }
  }
  __syncthreads();

  if (MODE == 0 && bn == 1) {
    #pragma unroll
    for (int h = 0; h < 2; ++h)
      #pragma unroll
      for (int ct = 0; ct < 4; ++ct) {
        const int col = h*64 + ct*16 + c;
        const float bv = bias[col];
        #pragma unroll
        for (int rt = 0; rt < 2; ++rt)
          #pragma unroll
          for (int i = 0; i < 4; ++i) {
            const int row = r0 + wave*32 + rt*16 + q*4 + i;
            if (row < N_NODES) outf[row*FOUT + col] = acc[h][rt][ct][i] + bv;
          }
      }
  } else {
    const int ncols = (MODE == 0) ? FOUT : FG;
    #pragma unroll
    for (int h = 0; h < 2; ++h) {
      if (h == 1) __syncthreads();         // half-0 scratch reads done
      #pragma unroll
      for (int rt = 0; rt < 2; ++rt)
        #pragma unroll
        for (int ct = 0; ct < 4; ++ct)
          #pragma unroll
          for (int i = 0; i < 4; ++i) {
            const int lrow = wave*32 + rt*16 + q*4 + i;
            const int lcol = ct*16 + c;
            const float v = acc[h][rt][ct][i];
            const unsigned short hh = f2bfu(v);
            At0[lrow*64 + lcol] = hh;
            if (MODE == 0) At1[lrow*64 + lcol] = f2bfu(v - u2f((unsigned)hh << 16));
          }
      __syncthreads();
      #pragma unroll
      for (int rr = 0; rr < 4; ++rr) {
        const int row = rr*32 + srow;
        const int grow = r0 + row;
        if (grow < N_NODES) {
          const int dst = grow*ncols + bn*128 + h*64 + sg*8;
          *(uint4*)&o_h[dst] = *(const uint4*)&At0[row*64 + sg*8];
          if (MODE == 0) *(uint4*)&o_l[dst] = *(const uint4*)&At1[row*64 + sg*8];
        }
      }
    }
  }
}

// ---------------- U1: kgemm0 (blocks 0..G0B-1)  UNION  k_s (blocks G0B..) ----------------
__global__ __launch_bounds__(256) void u1(
    const float* __restrict__ x,
    const unsigned short* __restrict__ Wch, const unsigned short* __restrict__ Wcl,
    const double* __restrict__ vsrc, const double* __restrict__ vtrg,
    double* __restrict__ ssrc, double* __restrict__ strg,
    const float* __restrict__ bias, float* __restrict__ outf,
    unsigned short* __restrict__ projh, unsigned short* __restrict__ projl)
{
  __shared__ unsigned short At[2][128*64];
  __shared__ unsigned short Bt[2][64*64];
  const int bid = blockIdx.x;
  if (bid < G0B) {
    gemm_body<FIN,0>(At[0], At[1], Bt[0], Bt[1], bid % GM, bid / GM,
                     x, (const unsigned short*)0, (const unsigned short*)0,
                     Wch, Wcl, bias, outf, projh, projl);
  } else {
    const int kid = bid - G0B;             // 0..KSB-1, 64 nodes each
    const int wave = threadIdx.x >> 6, lane = threadIdx.x & 63;
    #pragma unroll 4
    for (int i = 0; i < 16; ++i) {
      const int n = kid*64 + wave*16 + i;
      if (n < N_NODES) {
        const float4 xv = *(const float4*)&x[n*FIN + lane*4];
        const double x0 = xv.x, x1 = xv.y, x2 = xv.z, x3 = xv.w;
        double a = x0*vsrc[lane*4] + x1*vsrc[lane*4+1] + x2*vsrc[lane*4+2] + x3*vsrc[lane*4+3];
        double b = x0*vtrg[lane*4] + x1*vtrg[lane*4+1] + x2*vtrg[lane*4+2] + x3*vtrg[lane*4+3];
        #pragma unroll
        for (int off = 32; off > 0; off >>= 1) {
          a += __shfl_down(a, off, 64);
          b += __shfl_down(b, off, 64);
        }
        if (lane == 0) { ssrc[n] = a; strg[n] = b; }
      }
    }
  }
}

// ---------------- U2: kgemm1 (blocks 0..G1B-1)  UNION  k34 (blocks G1B..) ----------------
__global__ __launch_bounds__(256) void u2(
    const unsigned short* __restrict__ projh, const unsigned short* __restrict__ projl,
    const unsigned short* __restrict__ wihh, const unsigned short* __restrict__ wihl,
    unsigned short* __restrict__ Gh,
    const double* __restrict__ ssrc, const double* __restrict__ strg,
    const int* __restrict__ esrc, const int* __restrict__ etrg,
    float* __restrict__ atts, int* __restrict__ srcs)
{
  __shared__ unsigned short At[2][128*64];
  __shared__ unsigned short Bt[2][64*64];
  const int bid = blockIdx.x;
  if (bid < G1B) {
    gemm_body<HID,1>(At[0], At[1], Bt[0], Bt[1], bid % GM, bid / GM,
                     (const float*)0, projh, projl,
                     wihh, wihl, (const float*)0, (float*)0,
                     Gh, (unsigned short*)0);
  } else {
    // k34: fused scores + per-node-max softmax + rank (shift-invariance)
    const int n = (bid - G1B)*256 + threadIdx.x;
    if (n < N_NODES) {
      const double stn = strg[etrg[n*DEG]];
      double sc[DEG]; int si[DEG];
      double mx = -1.0e300;
      #pragma unroll
      for (int j = 0; j < DEG; ++j) {
        const int s = esrc[n*DEG + j];
        double v = ssrc[s] + stn;
        v = (v > 0.0) ? v : 0.2*v;
        sc[j] = v;
        mx = (v > mx) ? v : mx;
        si[j] = s;
      }
      const float mxf = (float)mx;
      float av[DEG]; float sum = 0.f;
      #pragma unroll
      for (int j = 0; j < DEG; ++j) {
        av[j] = __expf((float)sc[j] - mxf);
        sum += av[j];
      }
      const float inv = 1.f/(sum + 1e-16f);
      #pragma unroll
      for (int j = 0; j < DEG; ++j) {
        int r = 0;
        #pragma unroll
        for (int k = 0; k < DEG; ++k)
          r += (sc[k] > sc[j]) || (sc[k] == sc[j] && k > j);
        atts[n*DEG + r] = av[j]*inv;
        srcs[n*DEG + r] = si[j]*FG;     // premultiplied gather offset
      }
    }
  }
}

// ---------------- K5: single-team 512-thread MFMA LSTM, 2 blocks/CU, static stride ----------------
// Fused-denominator activations (5 exp + 3 rcp per row).
__global__ __launch_bounds__(512, 4) void k5_lstm(
    const __hip_bfloat16* __restrict__ G, const float* __restrict__ whh,
    const float* __restrict__ bih, const float* __restrict__ bhh,
    const float* __restrict__ atts, const int* __restrict__ srcs,
    float* __restrict__ out)
{
  __shared__ unsigned short Bs[32768];          // 64 KB: gates 2,3 frags
  __shared__ unsigned short hbuf[2][16*128];    // 8 KB ping-pong
  __shared__ float attb[16][16];                // 1 KB
  __shared__ int   srcb[16][16];                // 1 KB

  const int tid  = threadIdx.x;
  const int wave = tid >> 6;       // 0..7
  const int lane = tid & 63;
  const int c    = lane & 15;
  const int q    = lane >> 4;
  const int fcol = wave*16 + c;
  const int nb0  = q*4;

  // stage gates 2,3 of whh -> Bs in MFMA-fragment order (once; 32 KB fp32, L2-resident)
  #pragma unroll
  for (int j = 0; j < 8; ++j) {
    const int s   = tid + j*512;            // 4096 slots of 16 B
    const int sg_ = s >> 11, skt = (s >> 9) & 3, sw8 = (s >> 6) & 7, sl = s & 63;
    const float* p = whh + (((sg_ + 2)*128 + sw8*16 + (sl & 15))*128 + skt*32 + (sl >> 4)*8);
    const float4 v0 = *(const float4*)p;
    const float4 v1 = *(const float4*)(p + 4);
    union { unsigned short us[8]; uint4 u4; } P;
    P.us[0]=f2bfu(v0.x); P.us[1]=f2bfu(v0.y); P.us[2]=f2bfu(v0.z); P.us[3]=f2bfu(v0.w);
    P.us[4]=f2bfu(v1.x); P.us[5]=f2bfu(v1.y); P.us[6]=f2bfu(v1.z); P.us[7]=f2bfu(v1.w);
    *(uint4*)&Bs[s*8] = P.u4;
  }

  // gates 0,1 of whh in registers (32 regs)
  FU Brg[2][4];
  #pragma unroll
  for (int g = 0; g < 2; ++g) {
    const float* wr = whh + (g*HID + fcol)*HID + q*8;
    #pragma unroll
    for (int kt = 0; kt < 4; ++kt) {
      const float4 w0 = *(const float4*)(wr + kt*32);
      const float4 w1 = *(const float4*)(wr + kt*32 + 4);
      Brg[g][kt].us[0]=f2bfu(w0.x); Brg[g][kt].us[1]=f2bfu(w0.y);
      Brg[g][kt].us[2]=f2bfu(w0.z); Brg[g][kt].us[3]=f2bfu(w0.w);
      Brg[g][kt].us[4]=f2bfu(w1.x); Brg[g][kt].us[5]=f2bfu(w1.y);
      Brg[g][kt].us[6]=f2bfu(w1.z); Brg[g][kt].us[7]=f2bfu(w1.w);
    }
  }

  float bsum[4];
  #pragma unroll
  for (int g = 0; g < 4; ++g) bsum[g] = bih[g*HID + fcol] + bhh[g*HID + fcol];

  int aoff[4];
  #pragma unroll
  for (int kt = 0; kt < 4; ++kt)
    aoff[kt] = c*128 + (((kt*4 + q) ^ c) & 15)*8;

  const unsigned short* Gu = (const unsigned short*)G;

  for (int chunk = blockIdx.x; chunk < NCHUNK; chunk += K5GRID) {
    const int nb = chunk * 16;
    __syncthreads();   // (1) prev chunk's attb/srcb/hbuf readers done (covers Bs-ready on entry)
    if (tid < 256) {
      ((float*)attb)[tid] = atts[nb*DEG + tid];
      ((int*)  srcb)[tid] = srcs[nb*DEG + tid];
    }
    __syncthreads();   // (2) attb/srcb ready; separates prev hbuf reads from t=0 writes

    float cst[4] = {0.f,0.f,0.f,0.f};
    float hv[4]  = {0.f,0.f,0.f,0.f};
    uint2 pf[4];
    #pragma unroll
    for (int r = 0; r < 4; ++r) {
      const int so = srcb[nb0 + r][0];
      pf[r] = *(const uint2*)(Gu + (size_t)so + fcol*4);
    }

    #pragma unroll 4
    for (int t = 0; t < DEG; ++t) {
      uint2 cur[4]; float at[4];
      #pragma unroll
      for (int r = 0; r < 4; ++r) { cur[r] = pf[r]; at[r] = attb[nb0 + r][t]; }
      if (t < DEG-1) {
        #pragma unroll
        for (int r = 0; r < 4; ++r) {
          const int so = srcb[nb0 + r][t+1];
          pf[r] = *(const uint2*)(Gu + (size_t)so + fcol*4);
        }
      }
      f32x4 acc[4];
      #pragma unroll
      for (int r = 0; r < 4; ++r) {
        acc[0][r] = bsum[0] + at[r]*bflo(cur[r].x);
        acc[1][r] = bsum[1] + at[r]*bfhi(cur[r].x);
        acc[2][r] = bsum[2] + at[r]*bflo(cur[r].y);
        acc[3][r] = bsum[3] + at[r]*bfhi(cur[r].y);
      }
      if (t > 0) {
        __syncthreads();                        // (3) h(t-1) visible
        const unsigned short* hb = hbuf[(t-1) & 1];
        FU A[4];
        #pragma unroll
        for (int kt = 0; kt < 4; ++kt) A[kt].u4 = *(const uint4*)(hb + aoff[kt]);
        // gates 0,1 from registers
        #pragma unroll
        for (int g = 0; g < 2; ++g) {
          #pragma unroll
          for (int kt = 0; kt < 4; ++kt)
            acc[g] = __builtin_amdgcn_mfma_f32_16x16x32_bf16(A[kt].bf, Brg[g][kt].bf, acc[g], 0, 0, 0);
        }
        // gates 2,3 from LDS
        #pragma unroll
        for (int g = 2; g < 4; ++g) {
          FU Bf[4];
          #pragma unroll
          for (int kt = 0; kt < 4; ++kt)
            Bf[kt].u4 = *(const uint4*)&Bs[((((g-2)*4 + kt)*8 + wave)*64 + lane)*8];
          #pragma unroll
          for (int kt = 0; kt < 4; ++kt)
            acc[g] = __builtin_amdgcn_mfma_f32_16x16x32_bf16(A[kt].bf, Bf[kt].bf, acc[g], 0, 0, 0);
        }
      }
      #pragma unroll
      for (int r = 0; r < 4; ++r) {
        // fused-denominator LSTM pointwise: 5 exp + 3 rcp
        const float e0 = __expf(-acc[0][r]);                       // ig denom
        const float e1 = __expf(-acc[1][r]);                       // fg denom
        const float z2 = fminf(fmaxf(2.f*acc[2][r], -30.f), 30.f);
        const float e2 = __expf(z2);                               // gg
        const float e3 = __expf(-acc[3][r]);                       // og denom
        const float fg = rcpf(1.f + e1);
        const float iggg = (e2 - 1.f) * rcpf((1.f + e0)*(e2 + 1.f));
        cst[r] = fg*cst[r] + iggg;
        const float ec = __expf(2.f*cst[r]);                       // |cst|<=16 -> finite
        hv[r] = (ec - 1.f) * rcpf((1.f + e3)*(ec + 1.f));
      }
      if (t < DEG-1) {
        unsigned short* hw = hbuf[t & 1];
        #pragma unroll
        for (int r = 0; r < 4; ++r) {
          const float other = __shfl_xor(hv[r], 1, 64);
          if ((c & 1) == 0) {
            const unsigned pack = (unsigned)f2bfu(hv[r]) | ((unsigned)f2bfu(other) << 16);
            const int node = nb0 + r;
            const int k = fcol;
            const int half = node*128 + (((k >> 3) ^ node) & 15)*8 + (k & 7);
            *(unsigned*)(hw + half) = pack;
          }
        }
      }
    }
    #pragma unroll
    for (int r = 0; r < 4; ++r) {
      const int node = nb + nb0 + r;
      const float v = hv[r] + out[node*HID + fcol];
      out[node*HID + fcol] = (v > 0.f) ? v : 0.01f*v;
    }
  }
}

// ---------------- launch ----------------
// 4 launches: k_w(513 blk, converts W once) -> U1(gemm0 + k_s) -> U2(gemm1 + k34) -> k5.
// ws layout (bytes):
//  Gh     @ 256        (51.2 MB)
//  projh  @ 51200256   (12.8 MB)
//  projl  @ 64000256   (12.8 MB)   -> atts (3.2) + srcs (3.2) alias after U2's gemm done
//  Wch    @ 76800256  Wcl @ 76931328  wihh @ 77062400  wihl @ 77193472 (128 KB each)
//  vsrc   @ 77324544  vtrg @ 77326592 (2 KB each)
//  ssrc   @ 77328640  strg @ 77728640 (400 KB each)   end ~78.1 MB
extern "C" void kernel_launch(void* const* d_in, const int* in_sizes, int n_in,
                              void* d_out, int out_size, void* d_ws, size_t ws_size,
                              hipStream_t stream)
{
  (void)in_sizes; (void)n_in; (void)out_size; (void)ws_size;
  const float* x     = (const float*)d_in[0];
  const float* Wp    = (const float*)d_in[1];
  const float* a_src = (const float*)d_in[2];
  const float* a_trg = (const float*)d_in[3];
  const float* Ws    = (const float*)d_in[4];
  const float* bias  = (const float*)d_in[5];
  const float* wih_b = (const float*)d_in[10];
  const float* whh_b = (const float*)d_in[11];
  const float* bih_b = (const float*)d_in[12];
  const float* bhh_b = (const float*)d_in[13];
  const int*   eidx  = (const int*)d_in[14];
  const int* esrc = eidx;
  const int* etrg = eidx + NEDGE;
  float* out = (float*)d_out;

  unsigned char* ws = (unsigned char*)d_ws;
  unsigned short* Gh   = (unsigned short*)(ws + 256);
  unsigned short* projh= (unsigned short*)(ws + 51200256);
  unsigned short* projl= (unsigned short*)(ws + 64000256);
  float*          atts = (float*) (ws + 64000256);             // aliases projl
  int*            srcs = (int*)   (ws + 67200256);
  unsigned short* Wch  = (unsigned short*)(ws + 76800256);
  unsigned short* Wcl  = (unsigned short*)(ws + 76931328);
  unsigned short* wihh = (unsigned short*)(ws + 77062400);
  unsigned short* wihl = (unsigned short*)(ws + 77193472);
  double*         vsrc = (double*)(ws + 77324544);
  double*         vtrg = (double*)(ws + 77326592);
  double*         ssrc = (double*)(ws + 77328640);
  double*         strg = (double*)(ws + 77728640);

  k_w<<<dim3(513), dim3(256), 0, stream>>>(Wp, Ws, wih_b, a_src, a_trg,
                                           Wch, Wcl, wihh, wihl, vsrc, vtrg);
  u1<<<dim3(G0B + KSB), dim3(256), 0, stream>>>(
      x, Wch, Wcl, vsrc, vtrg, ssrc, strg, bias, out, projh, projl);
  u2<<<dim3(G1B + K34B), dim3(256), 0, stream>>>(
      projh, projl, wihh, wihl, Gh, ssrc, strg, esrc, etrg, atts, srcs);
  k5_lstm<<<dim3(K5GRID), dim3(512), 0, stream>>>(
      (const __hip_bfloat16*)Gh, whh_b, bih_b, bhh_b, atts, srcs, out);
}

// Round 15
// 420.054 us; speedup vs baseline: 1.0237x; 1.0237x over previous
//
#include <hip/hip_runtime.h>
#include <hip/hip_bf16.h>
#include <math.h>

#define N_NODES 50000
#define DEG 16
#define FIN 256
#define FOUT 128
#define HID 128
#define FG 512            // 4*HID
#define NEDGE (N_NODES*DEG)
#define NCHUNK (N_NODES/16)   // 3125 exactly
#define K5GRID 512            // 2 blocks/CU, independent barrier domains
#define GM 391                // (N_NODES+127)/128
#define G0B (GM*2)            // kgemm0 blocks (bn = 0,1)
#define G1B (GM*4)            // kgemm1 blocks (bn = 0..3)
#define KSB 782               // k_s blocks (64 rows each; 782*64 = 50048 >= N)
#define K34B 196              // k34 blocks ((N+255)/256)

typedef __bf16 bf16x8 __attribute__((ext_vector_type(8)));
typedef __bf16 bf16x2 __attribute__((ext_vector_type(2)));
typedef float  f32x4  __attribute__((ext_vector_type(4)));

// ---------------- helpers ----------------
static __device__ __forceinline__ float u2f(unsigned int u){ union {unsigned int u; float f;} v; v.u=u; return v.f; }
static __device__ __forceinline__ unsigned int f2u(float f){ union {float f; unsigned int u;} v; v.f=f; return v.u; }
// native RNE float->bf16 (compiler emits v_cvt_pk_bf16_f32; same RNE bits as
// the manual add-0x7fff sequence, 1 VALU inst instead of 3)
static __device__ __forceinline__ unsigned short f2bfu(float f){
  union { __bf16 b; unsigned short u; } v; v.b = (__bf16)f; return v.u;
}
// two floats -> packed bf16x2 dword (one v_cvt_pk_bf16_f32)
static __device__ __forceinline__ unsigned pack2bf(float lo, float hi){
  union { bf16x2 b; unsigned u; } v;
  v.b[0] = (__bf16)lo; v.b[1] = (__bf16)hi;
  return v.u;
}
static __device__ __forceinline__ float bflo(unsigned int u){ return u2f(u << 16); }
static __device__ __forceinline__ float bfhi(unsigned int u){ return u2f(u & 0xffff0000u); }
// fast reciprocal: v_rcp_f32 (<=1 ulp) instead of IEEE div sequence
static __device__ __forceinline__ float rcpf(float x){ return __builtin_amdgcn_rcpf(x); }

// async global->LDS copy, 16B/lane, wave-uniform LDS base + lane*16 dest
static __device__ __forceinline__ void gl_lds16(const void* g, void* l){
  __builtin_amdgcn_global_load_lds(
      (const __attribute__((address_space(1))) unsigned int*)g,
      (__attribute__((address_space(3))) unsigned int*)l, 16, 0, 0);
}

// 8x fp32 -> split-bf16 hi/lo planes
static __device__ __forceinline__ void cvt8(const float4 v0, const float4 v1, uint4* H4, uint4* L4){
  union { unsigned short us[8]; uint4 u4; } H, L;
  H.us[0]=f2bfu(v0.x); L.us[0]=f2bfu(v0.x - u2f((unsigned)H.us[0] << 16));
  H.us[1]=f2bfu(v0.y); L.us[1]=f2bfu(v0.y - u2f((unsigned)H.us[1] << 16));
  H.us[2]=f2bfu(v0.z); L.us[2]=f2bfu(v0.z - u2f((unsigned)H.us[2] << 16));
  H.us[3]=f2bfu(v0.w); L.us[3]=f2bfu(v0.w - u2f((unsigned)H.us[3] << 16));
  H.us[4]=f2bfu(v1.x); L.us[4]=f2bfu(v1.x - u2f((unsigned)H.us[4] << 16));
  H.us[5]=f2bfu(v1.y); L.us[5]=f2bfu(v1.y - u2f((unsigned)H.us[5] << 16));
  H.us[6]=f2bfu(v1.z); L.us[6]=f2bfu(v1.z - u2f((unsigned)H.us[6] << 16));
  H.us[7]=f2bfu(v1.w); L.us[7]=f2bfu(v1.w - u2f((unsigned)H.us[7] << 16));
  *H4 = H.u4; *L4 = L.u4;
}

union FU { bf16x8 bf; unsigned short us[8]; uint4 u4; };

// ---------------- KW: weight converts (ONCE) + v = W^T a (double) ----------------
__global__ __launch_bounds__(256) void k_w(
    const float* __restrict__ Wp, const float* __restrict__ Ws,
    const float* __restrict__ wih, const float* __restrict__ a_src, const float* __restrict__ a_trg,
    unsigned short* __restrict__ Wch, unsigned short* __restrict__ Wcl,
    unsigned short* __restrict__ wihh, unsigned short* __restrict__ wihl,
    double* __restrict__ vsrc, double* __restrict__ vtrg)
{
  const int b = blockIdx.x, tid = threadIdx.x;
  if (b < 256) {
    const float* src = (b < 128) ? (Wp + b*FIN) : (Ws + (b-128)*FIN);
    const float v = src[tid];
    const unsigned short h = f2bfu(v);
    Wch[b*FIN + tid] = h;
    Wcl[b*FIN + tid] = f2bfu(v - u2f((unsigned)h << 16));
  } else if (b < 512) {
    const int row = (b-256)*2 + (tid >> 7);
    const int k   = tid & 127;
    const float v = wih[row*HID + k];
    const unsigned short h = f2bfu(v);
    wihh[row*HID + k] = h;
    wihl[row*HID + k] = f2bfu(v - u2f((unsigned)h << 16));
  } else {
    const int k = tid;
    double s1 = 0.0, s2 = 0.0;
    for (int i = 0; i < FOUT; ++i) {
      const double w = (double)Wp[i*FIN + k];
      s1 += (double)a_src[i] * w;
      s2 += (double)a_trg[i] * w;
    }
    vsrc[k] = s1; vtrg[k] = s2;
  }
}

// ---------------- GEMM body: split-bf16 MFMA, 128x128 tile, 2 half-passes ----------------
template<int KD, int MODE>
static __device__ __forceinline__ void gemm_body(
    unsigned short* __restrict__ At0, unsigned short* __restrict__ At1,
    unsigned short* __restrict__ Bt0, unsigned short* __restrict__ Bt1,
    const int bm, const int bn,
    const float* __restrict__ Af32,
    const unsigned short* __restrict__ Ah_g, const unsigned short* __restrict__ Al_g,
    const unsigned short* __restrict__ Bh_g, const unsigned short* __restrict__ Bl_g,
    const float* __restrict__ bias, float* __restrict__ outf,
    unsigned short* __restrict__ o_h, unsigned short* __restrict__ o_l)
{
  const int tid = threadIdx.x;
  const int r0 = bm*128;
  const int wave = tid >> 6, lane = tid & 63, c = lane & 15, q = lane >> 4;
  const int srow = tid >> 3, sg = tid & 7;

  f32x4 acc[2][2][4];   // [half][rt][ct]
  #pragma unroll
  for (int h = 0; h < 2; ++h)
    #pragma unroll
    for (int rt = 0; rt < 2; ++rt)
      #pragma unroll
      for (int ct = 0; ct < 4; ++ct) acc[h][rt][ct] = (f32x4){0.f,0.f,0.f,0.f};

  for (int kt = 0; kt < KD/64; ++kt) {
    const int k0 = kt*64;
    __syncthreads();                       // prev iteration's At/Bt reads done
    if (MODE == 0) {
      #pragma unroll
      for (int rr = 0; rr < 4; ++rr) {
        const int row = rr*32 + srow;
        int grow = r0 + row; if (grow >= N_NODES) grow = N_NODES-1;
        const int ga = grow*KD + k0 + sg*8;
        const int la = row*64 + (((sg ^ (row & 7))) << 3);
        cvt8(*(const float4*)&Af32[ga], *(const float4*)&Af32[ga + 4],
             (uint4*)&At0[la], (uint4*)&At1[la]);
      }
    } else {
      #pragma unroll
      for (int rr = 0; rr < 4; ++rr) {
        const int row = rr*32 + wave*8 + (lane >> 3);
        int grow = r0 + row; if (grow >= N_NODES) grow = N_NODES-1;
        const int sgE = (lane & 7) ^ (row & 7);
        const int ga = grow*KD + k0 + sgE*8;
        const int la = (rr*32 + wave*8)*64;          // wave-uniform
        gl_lds16(&Ah_g[ga], &At0[la]);
        gl_lds16(&Al_g[ga], &At1[la]);
      }
    }

    #pragma unroll
    for (int h = 0; h < 2; ++h) {
      if (h == 1) __syncthreads();         // half-0 Bt reads done before overwrite
      // B half-tile from precomputed planes via gl_lds16
      #pragma unroll
      for (int rr = 0; rr < 2; ++rr) {
        const int row = rr*32 + wave*8 + (lane >> 3);
        const int j = bn*128 + h*64 + row;
        int wr;
        if (MODE == 0) wr = j;                        // Wch = [Wp;Ws], 256 rows
        else wr = (j & 3)*HID + (j >> 2);             // gate-interleaved wih
        const int sgE = (lane & 7) ^ (row & 7);
        const int ga = wr*KD + k0 + sgE*8;
        const int la = (rr*32 + wave*8)*64;           // wave-uniform
        gl_lds16(&Bh_g[ga], &Bt0[la]);
        gl_lds16(&Bl_g[ga], &Bt1[la]);
      }
      __syncthreads();                     // At (h==0) / Bt ready

      #pragma unroll
      for (int s = 0; s < 2; ++s) {
        FU Af[2][2], Bf[4][2];
        #pragma unroll
        for (int rt = 0; rt < 2; ++rt) {
          const int row = wave*32 + rt*16 + c;
          const int ad = row*64 + (((((s<<2)+q) ^ (row & 7))) << 3);
          Af[rt][0].u4 = *(const uint4*)&At0[ad];
          Af[rt][1].u4 = *(const uint4*)&At1[ad];
        }
        #pragma unroll
        for (int ct = 0; ct < 4; ++ct) {
          const int row = ct*16 + c;
          const int ad = row*64 + (((((s<<2)+q) ^ (row & 7))) << 3);
          Bf[ct][0].u4 = *(const uint4*)&Bt0[ad];
          Bf[ct][1].u4 = *(const uint4*)&Bt1[ad];
        }
        #pragma unroll
        for (int rt = 0; rt < 2; ++rt)
          #pragma unroll
          for (int ct = 0; ct < 4; ++ct) {
            acc[h][rt][ct] = __builtin_amdgcn_mfma_f32_16x16x32_bf16(Af[rt][0].bf, Bf[ct][0].bf, acc[h][rt][ct], 0,0,0);
            acc[h][rt][ct] = __builtin_amdgcn_mfma_f32_16x16x32_bf16(Af[rt][1].bf, Bf[ct][0].bf, acc[h][rt][ct], 0,0,0);
            acc[h][rt][ct] = __builtin_amdgcn_mfma_f32_16x16x32_bf16(Af[rt][0].bf, Bf[ct][1].bf, acc[h][rt][ct], 0,0,0);
          }
      }
    }
  }
  __syncthreads();

  if (MODE == 0 && bn == 1) {
    #pragma unroll
    for (int h = 0; h < 2; ++h)
      #pragma unroll
      for (int ct = 0; ct < 4; ++ct) {
        const int col = h*64 + ct*16 + c;
        const float bv = bias[col];
        #pragma unroll
        for (int rt = 0; rt < 2; ++rt)
          #pragma unroll
          for (int i = 0; i < 4; ++i) {
            const int row = r0 + wave*32 + rt*16 + q*4 + i;
            if (row < N_NODES) outf[row*FOUT + col] = acc[h][rt][ct][i] + bv;
          }
      }
  } else {
    const int ncols = (MODE == 0) ? FOUT : FG;
    #pragma unroll
    for (int h = 0; h < 2; ++h) {
      if (h == 1) __syncthreads();         // half-0 scratch reads done
      #pragma unroll
      for (int rt = 0; rt < 2; ++rt)
        #pragma unroll
        for (int ct = 0; ct < 4; ++ct)
          #pragma unroll
          for (int i = 0; i < 4; ++i) {
            const int lrow = wave*32 + rt*16 + q*4 + i;
            const int lcol = ct*16 + c;
            const float v = acc[h][rt][ct][i];
            const unsigned short hh = f2bfu(v);
            At0[lrow*64 + lcol] = hh;
            if (MODE == 0) At1[lrow*64 + lcol] = f2bfu(v - u2f((unsigned)hh << 16));
          }
      __syncthreads();
      #pragma unroll
      for (int rr = 0; rr < 4; ++rr) {
        const int row = rr*32 + srow;
        const int grow = r0 + row;
        if (grow < N_NODES) {
          const int dst = grow*ncols + bn*128 + h*64 + sg*8;
          *(uint4*)&o_h[dst] = *(const uint4*)&At0[row*64 + sg*8];
          if (MODE == 0) *(uint4*)&o_l[dst] = *(const uint4*)&At1[row*64 + sg*8];
        }
      }
    }
  }
}

// ---------------- U1: kgemm0 (blocks 0..G0B-1)  UNION  k_s (blocks G0B..) ----------------
__global__ __launch_bounds__(256) void u1(
    const float* __restrict__ x,
    const unsigned short* __restrict__ Wch, const unsigned short* __restrict__ Wcl,
    const double* __restrict__ vsrc, const double* __restrict__ vtrg,
    double* __restrict__ ssrc, double* __restrict__ strg,
    const float* __restrict__ bias, float* __restrict__ outf,
    unsigned short* __restrict__ projh, unsigned short* __restrict__ projl)
{
  __shared__ unsigned short At[2][128*64];
  __shared__ unsigned short Bt[2][64*64];
  const int bid = blockIdx.x;
  if (bid < G0B) {
    gemm_body<FIN,0>(At[0], At[1], Bt[0], Bt[1], bid % GM, bid / GM,
                     x, (const unsigned short*)0, (const unsigned short*)0,
                     Wch, Wcl, bias, outf, projh, projl);
  } else {
    const int kid = bid - G0B;             // 0..KSB-1, 64 nodes each
    const int wave = threadIdx.x >> 6, lane = threadIdx.x & 63;
    #pragma unroll 4
    for (int i = 0; i < 16; ++i) {
      const int n = kid*64 + wave*16 + i;
      if (n < N_NODES) {
        const float4 xv = *(const float4*)&x[n*FIN + lane*4];
        const double x0 = xv.x, x1 = xv.y, x2 = xv.z, x3 = xv.w;
        double a = x0*vsrc[lane*4] + x1*vsrc[lane*4+1] + x2*vsrc[lane*4+2] + x3*vsrc[lane*4+3];
        double b = x0*vtrg[lane*4] + x1*vtrg[lane*4+1] + x2*vtrg[lane*4+2] + x3*vtrg[lane*4+3];
        #pragma unroll
        for (int off = 32; off > 0; off >>= 1) {
          a += __shfl_down(a, off, 64);
          b += __shfl_down(b, off, 64);
        }
        if (lane == 0) { ssrc[n] = a; strg[n] = b; }
      }
    }
  }
}

// ---------------- U2: kgemm1 (blocks 0..G1B-1)  UNION  k34 (blocks G1B..) ----------------
__global__ __launch_bounds__(256) void u2(
    const unsigned short* __restrict__ projh, const unsigned short* __restrict__ projl,
    const unsigned short* __restrict__ wihh, const unsigned short* __restrict__ wihl,
    unsigned short* __restrict__ Gh,
    const double* __restrict__ ssrc, const double* __restrict__ strg,
    const int* __restrict__ esrc, const int* __restrict__ etrg,
    float* __restrict__ atts, int* __restrict__ srcs)
{
  __shared__ unsigned short At[2][128*64];
  __shared__ unsigned short Bt[2][64*64];
  const int bid = blockIdx.x;
  if (bid < G1B) {
    gemm_body<HID,1>(At[0], At[1], Bt[0], Bt[1], bid % GM, bid / GM,
                     (const float*)0, projh, projl,
                     wihh, wihl, (const float*)0, (float*)0,
                     Gh, (unsigned short*)0);
  } else {
    // k34: fused scores + per-node-max softmax + rank (shift-invariance)
    const int n = (bid - G1B)*256 + threadIdx.x;
    if (n < N_NODES) {
      const double stn = strg[etrg[n*DEG]];
      double sc[DEG]; int si[DEG];
      double mx = -1.0e300;
      #pragma unroll
      for (int j = 0; j < DEG; ++j) {
        const int s = esrc[n*DEG + j];
        double v = ssrc[s] + stn;
        v = (v > 0.0) ? v : 0.2*v;
        sc[j] = v;
        mx = (v > mx) ? v : mx;
        si[j] = s;
      }
      const float mxf = (float)mx;
      float av[DEG]; float sum = 0.f;
      #pragma unroll
      for (int j = 0; j < DEG; ++j) {
        av[j] = __expf((float)sc[j] - mxf);
        sum += av[j];
      }
      const float inv = 1.f/(sum + 1e-16f);
      #pragma unroll
      for (int j = 0; j < DEG; ++j) {
        int r = 0;
        #pragma unroll
        for (int k = 0; k < DEG; ++k)
          r += (sc[k] > sc[j]) || (sc[k] == sc[j] && k > j);
        atts[n*DEG + r] = av[j]*inv;
        srcs[n*DEG + r] = si[j]*FG;     // premultiplied gather offset
      }
    }
  }
}

// ---------------- K5: single-team 512-thread MFMA LSTM, 2 blocks/CU, static stride ----------------
// Fused-denominator activations (5 exp + 3 rcp per row); h-pack via one
// v_cvt_pk_bf16_f32 per r (pack2bf) instead of 2x manual RNE + or/shift.
__global__ __launch_bounds__(512, 4) void k5_lstm(
    const __hip_bfloat16* __restrict__ G, const float* __restrict__ whh,
    const float* __restrict__ bih, const float* __restrict__ bhh,
    const float* __restrict__ atts, const int* __restrict__ srcs,
    float* __restrict__ out)
{
  __shared__ unsigned short Bs[32768];          // 64 KB: gates 2,3 frags
  __shared__ unsigned short hbuf[2][16*128];    // 8 KB ping-pong
  __shared__ float attb[16][16];                // 1 KB
  __shared__ int   srcb[16][16];                // 1 KB

  const int tid  = threadIdx.x;
  const int wave = tid >> 6;       // 0..7
  const int lane = tid & 63;
  const int c    = lane & 15;
  const int q    = lane >> 4;
  const int fcol = wave*16 + c;
  const int nb0  = q*4;

  // stage gates 2,3 of whh -> Bs in MFMA-fragment order (once; 32 KB fp32, L2-resident)
  #pragma unroll
  for (int j = 0; j < 8; ++j) {
    const int s   = tid + j*512;            // 4096 slots of 16 B
    const int sg_ = s >> 11, skt = (s >> 9) & 3, sw8 = (s >> 6) & 7, sl = s & 63;
    const float* p = whh + (((sg_ + 2)*128 + sw8*16 + (sl & 15))*128 + skt*32 + (sl >> 4)*8);
    const float4 v0 = *(const float4*)p;
    const float4 v1 = *(const float4*)(p + 4);
    union { unsigned short us[8]; uint4 u4; } P;
    P.us[0]=f2bfu(v0.x); P.us[1]=f2bfu(v0.y); P.us[2]=f2bfu(v0.z); P.us[3]=f2bfu(v0.w);
    P.us[4]=f2bfu(v1.x); P.us[5]=f2bfu(v1.y); P.us[6]=f2bfu(v1.z); P.us[7]=f2bfu(v1.w);
    *(uint4*)&Bs[s*8] = P.u4;
  }

  // gates 0,1 of whh in registers (32 regs)
  FU Brg[2][4];
  #pragma unroll
  for (int g = 0; g < 2; ++g) {
    const float* wr = whh + (g*HID + fcol)*HID + q*8;
    #pragma unroll
    for (int kt = 0; kt < 4; ++kt) {
      const float4 w0 = *(const float4*)(wr + kt*32);
      const float4 w1 = *(const float4*)(wr + kt*32 + 4);
      Brg[g][kt].us[0]=f2bfu(w0.x); Brg[g][kt].us[1]=f2bfu(w0.y);
      Brg[g][kt].us[2]=f2bfu(w0.z); Brg[g][kt].us[3]=f2bfu(w0.w);
      Brg[g][kt].us[4]=f2bfu(w1.x); Brg[g][kt].us[5]=f2bfu(w1.y);
      Brg[g][kt].us[6]=f2bfu(w1.z); Brg[g][kt].us[7]=f2bfu(w1.w);
    }
  }

  float bsum[4];
  #pragma unroll
  for (int g = 0; g < 4; ++g) bsum[g] = bih[g*HID + fcol] + bhh[g*HID + fcol];

  int aoff[4];
  #pragma unroll
  for (int kt = 0; kt < 4; ++kt)
    aoff[kt] = c*128 + (((kt*4 + q) ^ c) & 15)*8;

  const unsigned short* Gu = (const unsigned short*)G;

  for (int chunk = blockIdx.x; chunk < NCHUNK; chunk += K5GRID) {
    const int nb = chunk * 16;
    __syncthreads();   // (1) prev chunk's attb/srcb/hbuf readers done (covers Bs-ready on entry)
    if (tid < 256) {
      ((float*)attb)[tid] = atts[nb*DEG + tid];
      ((int*)  srcb)[tid] = srcs[nb*DEG + tid];
    }
    __syncthreads();   // (2) attb/srcb ready; separates prev hbuf reads from t=0 writes

    float cst[4] = {0.f,0.f,0.f,0.f};
    float hv[4]  = {0.f,0.f,0.f,0.f};
    uint2 pf[4];
    #pragma unroll
    for (int r = 0; r < 4; ++r) {
      const int so = srcb[nb0 + r][0];
      pf[r] = *(const uint2*)(Gu + (size_t)so + fcol*4);
    }

    #pragma unroll 4
    for (int t = 0; t < DEG; ++t) {
      uint2 cur[4]; float at[4];
      #pragma unroll
      for (int r = 0; r < 4; ++r) { cur[r] = pf[r]; at[r] = attb[nb0 + r][t]; }
      if (t < DEG-1) {
        #pragma unroll
        for (int r = 0; r < 4; ++r) {
          const int so = srcb[nb0 + r][t+1];
          pf[r] = *(const uint2*)(Gu + (size_t)so + fcol*4);
        }
      }
      f32x4 acc[4];
      #pragma unroll
      for (int r = 0; r < 4; ++r) {
        acc[0][r] = bsum[0] + at[r]*bflo(cur[r].x);
        acc[1][r] = bsum[1] + at[r]*bfhi(cur[r].x);
        acc[2][r] = bsum[2] + at[r]*bflo(cur[r].y);
        acc[3][r] = bsum[3] + at[r]*bfhi(cur[r].y);
      }
      if (t > 0) {
        __syncthreads();                        // (3) h(t-1) visible
        const unsigned short* hb = hbuf[(t-1) & 1];
        FU A[4];
        #pragma unroll
        for (int kt = 0; kt < 4; ++kt) A[kt].u4 = *(const uint4*)(hb + aoff[kt]);
        // gates 0,1 from registers
        #pragma unroll
        for (int g = 0; g < 2; ++g) {
          #pragma unroll
          for (int kt = 0; kt < 4; ++kt)
            acc[g] = __builtin_amdgcn_mfma_f32_16x16x32_bf16(A[kt].bf, Brg[g][kt].bf, acc[g], 0, 0, 0);
        }
        // gates 2,3 from LDS
        #pragma unroll
        for (int g = 2; g < 4; ++g) {
          FU Bf[4];
          #pragma unroll
          for (int kt = 0; kt < 4; ++kt)
            Bf[kt].u4 = *(const uint4*)&Bs[((((g-2)*4 + kt)*8 + wave)*64 + lane)*8];
          #pragma unroll
          for (int kt = 0; kt < 4; ++kt)
            acc[g] = __builtin_amdgcn_mfma_f32_16x16x32_bf16(A[kt].bf, Bf[kt].bf, acc[g], 0, 0, 0);
        }
      }
      #pragma unroll
      for (int r = 0; r < 4; ++r) {
        // fused-denominator LSTM pointwise: 5 exp + 3 rcp
        const float e0 = __expf(-acc[0][r]);                       // ig denom
        const float e1 = __expf(-acc[1][r]);                       // fg denom
        const float z2 = fminf(fmaxf(2.f*acc[2][r], -30.f), 30.f);
        const float e2 = __expf(z2);                               // gg
        const float e3 = __expf(-acc[3][r]);                       // og denom
        const float fg = rcpf(1.f + e1);
        const float iggg = (e2 - 1.f) * rcpf((1.f + e0)*(e2 + 1.f));
        cst[r] = fg*cst[r] + iggg;
        const float ec = __expf(2.f*cst[r]);                       // |cst|<=16 -> finite
        hv[r] = (ec - 1.f) * rcpf((1.f + e3)*(ec + 1.f));
      }
      if (t < DEG-1) {
        unsigned short* hw = hbuf[t & 1];
        #pragma unroll
        for (int r = 0; r < 4; ++r) {
          const float other = __shfl_xor(hv[r], 1, 64);
          if ((c & 1) == 0) {
            const unsigned pack = pack2bf(hv[r], other);   // one v_cvt_pk_bf16_f32
            const int node = nb0 + r;
            const int k = fcol;
            const int half = node*128 + (((k >> 3) ^ node) & 15)*8 + (k & 7);
            *(unsigned*)(hw + half) = pack;
          }
        }
      }
    }
    #pragma unroll
    for (int r = 0; r < 4; ++r) {
      const int node = nb + nb0 + r;
      const float v = hv[r] + out[node*HID + fcol];
      out[node*HID + fcol] = (v > 0.f) ? v : 0.01f*v;
    }
  }
}

// ---------------- launch ----------------
// 4 launches: k_w(513 blk) -> U1(gemm0 + k_s) -> U2(gemm1 + k34) -> k5.
extern "C" void kernel_launch(void* const* d_in, const int* in_sizes, int n_in,
                              void* d_out, int out_size, void* d_ws, size_t ws_size,
                              hipStream_t stream)
{
  (void)in_sizes; (void)n_in; (void)out_size; (void)ws_size;
  const float* x     = (const float*)d_in[0];
  const float* Wp    = (const float*)d_in[1];
  const float* a_src = (const float*)d_in[2];
  const float* a_trg = (const float*)d_in[3];
  const float* Ws    = (const float*)d_in[4];
  const float* bias  = (const float*)d_in[5];
  const float* wih_b = (const float*)d_in[10];
  const float* whh_b = (const float*)d_in[11];
  const float* bih_b = (const float*)d_in[12];
  const float* bhh_b = (const float*)d_in[13];
  const int*   eidx  = (const int*)d_in[14];
  const int* esrc = eidx;
  const int* etrg = eidx + NEDGE;
  float* out = (float*)d_out;

  unsigned char* ws = (unsigned char*)d_ws;
  unsigned short* Gh   = (unsigned short*)(ws + 256);
  unsigned short* projh= (unsigned short*)(ws + 51200256);
  unsigned short* projl= (unsigned short*)(ws + 64000256);
  float*          atts = (float*) (ws + 64000256);             // aliases projl
  int*            srcs = (int*)   (ws + 67200256);
  unsigned short* Wch  = (unsigned short*)(ws + 76800256);
  unsigned short* Wcl  = (unsigned short*)(ws + 76931328);
  unsigned short* wihh = (unsigned short*)(ws + 77062400);
  unsigned short* wihl = (unsigned short*)(ws + 77193472);
  double*         vsrc = (double*)(ws + 77324544);
  double*         vtrg = (double*)(ws + 77326592);
  double*         ssrc = (double*)(ws + 77328640);
  double*         strg = (double*)(ws + 77728640);

  k_w<<<dim3(513), dim3(256), 0, stream>>>(Wp, Ws, wih_b, a_src, a_trg,
                                           Wch, Wcl, wihh, wihl, vsrc, vtrg);
  u1<<<dim3(G0B + KSB), dim3(256), 0, stream>>>(
      x, Wch, Wcl, vsrc, vtrg, ssrc, strg, bias, out, projh, projl);
  u2<<<dim3(G1B + K34B), dim3(256), 0, stream>>>(
      projh, projl, wihh, wihl, Gh, ssrc, strg, esrc, etrg, atts, srcs);
  k5_lstm<<<dim3(K5GRID), dim3(512), 0, stream>>>(
      (const __hip_bfloat16*)Gh, whh_b, bih_b, bhh_b, atts, srcs, out);
}